// Round 1
// baseline (350.557 us; speedup 1.0000x reference)
//
#include <hip/hip_runtime.h>
#include <cstdint>
#include <cstddef>

#define NN  768
#define IND 64
#define HD  128
#define EFD 16
#define TT  3

// ---- monotonic uint encoding of float for atomicMax ----
__device__ __forceinline__ unsigned enc_f(float f){
    unsigned b = __float_as_uint(f);
    return (b & 0x80000000u) ? ~b : (b | 0x80000000u);
}
__device__ __forceinline__ float dec_f(unsigned e){
    return __uint_as_float((e & 0x80000000u) ? (e & 0x7FFFFFFFu) : ~e);
}
#define ENC_NEG_INF 0x007FFFFFu  // enc(-inf)

// ---------- init: preds[:,0,:] = state0, preds_stop[:,0,:] = 0 ----------
__global__ void init_ker(const float* __restrict__ states, float* __restrict__ out){
    int i = blockIdx.x * 256 + threadIdx.x;
    if (i < NN * IND){
        int n = i >> 6, c = i & 63;
        out[n * 256 + c] = states[i];          // preds[n][0][c]
    } else if (i < NN * IND + NN * 2){
        int j = i - NN * IND;
        int n = j >> 1, cc = j & 1;
        out[196608 + n * 8 + cc] = 0.f;        // preds_stop[n][0][cc]
    }
}

// ---------- z = [state|hidden] @ We + be ; also inits u_enc and meansum ----------
__global__ void z_ker(const float* __restrict__ state, const float* __restrict__ hid,
                      const float* __restrict__ We, const float* __restrict__ be,
                      float* __restrict__ z, unsigned* __restrict__ u_enc,
                      float* __restrict__ meansum, int haveHid){
    int tid = threadIdx.x;
    int n = tid & 127, mh = tid >> 7;
    int m = blockIdx.x * 2 + mh;
    float acc = be[n];
    const float* srow = state + m * IND;
    #pragma unroll
    for (int k = 0; k < IND; ++k) acc += srow[k] * We[k * HD + n];
    if (haveHid){
        const float* hrow = hid + m * HD;
        #pragma unroll
        for (int k = 0; k < HD; ++k) acc += hrow[k] * We[(IND + k) * HD + n];
    }
    z[m * HD + n] = acc;
    u_enc[m * HD + n] = ENC_NEG_INF;
    if (blockIdx.x == 0 && mh == 0) meansum[n] = 0.f;
}

// ---------- zsrc = z @ Wm[:128], zdst = z @ Wm[128:256] ----------
__global__ void zsd_ker(const float* __restrict__ z, const float* __restrict__ Wm,
                        float* __restrict__ zsrc, float* __restrict__ zdst){
    int tid = threadIdx.x;
    int h = tid & 127, which = tid >> 7;
    int m = blockIdx.x;
    const float* zrow = z + m * HD;
    const float* W = Wm + which * HD * HD;
    float acc = 0.f;
    #pragma unroll
    for (int k = 0; k < HD; ++k) acc += zrow[k] * W[k * HD + h];
    (which ? zdst : zsrc)[m * HD + h] = acc;
}

// ---------- fused einsum + max over i:  u_enc[j,h] = max_i enc(zsrc[i,h] + edges[i,j,:]·WmE[:,h]) ----------
__global__ __launch_bounds__(256)
void msgmax_ker(const float* __restrict__ edges, const float* __restrict__ zsrc,
                const float* __restrict__ Wm, unsigned* __restrict__ u_enc){
    const float* WmE = Wm + 2 * HD * HD;   // rows 256..271 of Wm
    int tid = threadIdx.x;
    int jl = tid >> 5, hg = tid & 31, h0 = hg * 4;
    int j = blockIdx.x * 8 + jl;
    int i0 = blockIdx.y * 48;

    float4 w[16];
    #pragma unroll
    for (int e = 0; e < 16; ++e)
        w[e] = *reinterpret_cast<const float4*>(&WmE[e * HD + h0]);

    float4 rmax = make_float4(-INFINITY, -INFINITY, -INFINITY, -INFINITY);

    for (int ii = 0; ii < 48; ++ii){
        int i = i0 + ii;
        const float4* ep = reinterpret_cast<const float4*>(&edges[((size_t)i * NN + j) * EFD]);
        float4 e0 = ep[0], e1 = ep[1], e2 = ep[2], e3 = ep[3];
        float4 acc = *reinterpret_cast<const float4*>(&zsrc[i * HD + h0]);
        float ev[16] = {e0.x, e0.y, e0.z, e0.w,
                        e1.x, e1.y, e1.z, e1.w,
                        e2.x, e2.y, e2.z, e2.w,
                        e3.x, e3.y, e3.z, e3.w};
        #pragma unroll
        for (int e = 0; e < 16; ++e){
            acc.x += ev[e] * w[e].x;
            acc.y += ev[e] * w[e].y;
            acc.z += ev[e] * w[e].z;
            acc.w += ev[e] * w[e].w;
        }
        rmax.x = fmaxf(rmax.x, acc.x);
        rmax.y = fmaxf(rmax.y, acc.y);
        rmax.z = fmaxf(rmax.z, acc.z);
        rmax.w = fmaxf(rmax.w, acc.w);
    }
    unsigned* up = u_enc + j * HD + h0;
    atomicMax(up + 0, enc_f(rmax.x));
    atomicMax(up + 1, enc_f(rmax.y));
    atomicMax(up + 2, enc_f(rmax.z));
    atomicMax(up + 3, enc_f(rmax.w));
}

// ---------- h_new = [z | (dec(u_enc)+zdst+bm)] @ Wu + bu ; partial column sums for mean ----------
__global__ void hnew_ker(const float* __restrict__ z, const float* __restrict__ zdst,
                         const unsigned* __restrict__ u_enc, const float* __restrict__ bm,
                         const float* __restrict__ Wu, const float* __restrict__ bu,
                         float* __restrict__ hid, float* __restrict__ meansum){
    __shared__ float sA[2][256];
    __shared__ float sP[256];
    int tid = threadIdx.x;
    int m0 = blockIdx.x * 2;
    #pragma unroll
    for (int r = 0; r < 2; ++r){
        int idx = tid + r * 256;
        int mm = idx >> 8, k = idx & 255;
        float v;
        if (k < HD) v = z[(m0 + mm) * HD + k];
        else {
            int kk = k - HD;
            v = dec_f(u_enc[(m0 + mm) * HD + kk]) + zdst[(m0 + mm) * HD + kk] + bm[kk];
        }
        sA[mm][k] = v;
    }
    __syncthreads();
    int h = tid & 127, mh = tid >> 7;
    float acc = bu[h];
    #pragma unroll 8
    for (int k = 0; k < 256; ++k) acc += sA[mh][k] * Wu[k * HD + h];
    hid[(m0 + mh) * HD + h] = acc;
    sP[tid] = acc;
    __syncthreads();
    if (mh == 0) atomicAdd(&meansum[h], sP[h] + sP[128 + h]);
}

// ---------- stop = sigmoid([h_new|mean]@Wt+bt) ; new_state = [h_new|z]@Wd+bd ----------
__global__ void out_ker(const float* __restrict__ hid, const float* __restrict__ z,
                        const float* __restrict__ meansum,
                        const float* __restrict__ Wt, const float* __restrict__ bt,
                        const float* __restrict__ Wd, const float* __restrict__ bd,
                        float* __restrict__ out, float* __restrict__ state_next, int t){
    __shared__ float sA[4][256];   // [mm][k]: k<128 -> h_new, k>=128 -> z
    __shared__ float sM[128];
    int tid = threadIdx.x;
    int m0 = blockIdx.x * 4;
    #pragma unroll
    for (int r = 0; r < 4; ++r){
        int idx = tid + r * 256;
        int mm = idx >> 8, k = idx & 255;
        sA[mm][k] = (k < HD) ? hid[(m0 + mm) * HD + k] : z[(m0 + mm) * HD + (k - HD)];
    }
    if (tid < 128) sM[tid] = meansum[tid] * (1.0f / 768.0f);
    __syncthreads();

    int c = tid & 63, mm = tid >> 6;
    float acc = bd[c];
    #pragma unroll 8
    for (int k = 0; k < 256; ++k) acc += sA[mm][k] * Wd[k * IND + c];
    int m = m0 + mm;
    state_next[m * IND + c] = acc;
    out[m * 256 + (t + 1) * IND + c] = acc;

    if (tid < 8){
        int mml = tid >> 1, cc = tid & 1;
        int m2 = m0 + mml;
        float a2 = bt[cc];
        #pragma unroll 8
        for (int k = 0; k < HD; ++k) a2 += sA[mml][k] * Wt[k * 2 + cc];
        #pragma unroll 8
        for (int k = 0; k < HD; ++k) a2 += sM[k] * Wt[(HD + k) * 2 + cc];
        out[196608 + m2 * 8 + (t + 1) * 2 + cc] = 1.f / (1.f + expf(-a2));
    }
}

extern "C" void kernel_launch(void* const* d_in, const int* in_sizes, int n_in,
                              void* d_out, int out_size, void* d_ws, size_t ws_size,
                              hipStream_t stream){
    const float* states = (const float*)d_in[0];
    const float* edges  = (const float*)d_in[1];
    const float* We = (const float*)d_in[2];
    const float* be = (const float*)d_in[3];
    const float* Wm = (const float*)d_in[4];
    const float* bm = (const float*)d_in[5];
    const float* Wu = (const float*)d_in[6];
    const float* bu = (const float*)d_in[7];
    const float* Wd = (const float*)d_in[8];
    const float* bd = (const float*)d_in[9];
    const float* Wt = (const float*)d_in[10];
    const float* bt = (const float*)d_in[11];
    float* out = (float*)d_out;

    float* ws = (float*)d_ws;
    float*    z       = ws;                    // 98304
    float*    zsrc    = ws + 98304;            // 98304
    float*    zdst    = ws + 196608;           // 98304
    unsigned* u_enc   = (unsigned*)(ws + 294912); // 98304
    float*    hid     = ws + 393216;           // 98304
    float*    state   = ws + 491520;           // 49152
    float*    meansum = ws + 540672;           // 128

    init_ker<<<198, 256, 0, stream>>>(states, out);

    for (int t = 0; t < TT; ++t){
        const float* st = (t == 0) ? states : state;
        z_ker<<<384, 256, 0, stream>>>(st, hid, We, be, z, u_enc, meansum, t > 0 ? 1 : 0);
        zsd_ker<<<768, 256, 0, stream>>>(z, Wm, zsrc, zdst);
        msgmax_ker<<<dim3(96, 16), 256, 0, stream>>>(edges, zsrc, Wm, u_enc);
        hnew_ker<<<384, 256, 0, stream>>>(z, zdst, u_enc, bm, Wu, bu, hid, meansum);
        out_ker<<<192, 256, 0, stream>>>(hid, z, meansum, Wt, bt, Wd, bd, out, state, t);
    }
}

// Round 2
// 272.183 us; speedup vs baseline: 1.2879x; 1.2879x over previous
//
#include <hip/hip_runtime.h>
#include <cstdint>
#include <cstddef>

#define NN  768
#define IND 64
#define HD  128
#define EFD 16
#define TT  3
#define NC  16      // i-chunks in msgmax
#define CHUNK 48    // 768/NC

typedef __attribute__((ext_vector_type(8)))  short short8;
typedef __attribute__((ext_vector_type(16))) float floatx16;

__device__ __forceinline__ unsigned short f2bf(float f){
    unsigned u = __float_as_uint(f);
    unsigned r = (u + 0x7FFFu + ((u >> 16) & 1u)) >> 16;
    return (unsigned short)r;
}

// ---------- one-time: edges f32 -> bf16 ----------
__global__ void conv_ker(const float* __restrict__ e, unsigned short* __restrict__ ebf){
    int gid = blockIdx.x * 256 + threadIdx.x;          // 2359296 threads, 4 elems each
    const float4 v = reinterpret_cast<const float4*>(e)[gid];
    uint2 p;
    p.x = (unsigned)f2bf(v.x) | ((unsigned)f2bf(v.y) << 16);
    p.y = (unsigned)f2bf(v.z) | ((unsigned)f2bf(v.w) << 16);
    reinterpret_cast<uint2*>(ebf)[gid] = p;
}

// ---------- init: preds[:,0,:] = state0, preds_stop[:,0,:] = 0 ----------
__global__ void init_ker(const float* __restrict__ states, float* __restrict__ out){
    int i = blockIdx.x * 256 + threadIdx.x;
    if (i < NN * IND){
        int n = i >> 6, c = i & 63;
        out[n * 256 + c] = states[i];
    } else if (i < NN * IND + NN * 2){
        int j = i - NN * IND;
        int n = j >> 1, cc = j & 1;
        out[196608 + n * 8 + cc] = 0.f;
    }
}

// ---------- fused: z = [state|hid]@We+be ; zsrc=z@WmS ; zdst=z@WmD ----------
__global__ __launch_bounds__(256)
void zfused_ker(const float* __restrict__ state, const float* __restrict__ hid,
                const float* __restrict__ We, const float* __restrict__ be,
                const float* __restrict__ Wm,
                float* __restrict__ z, float* __restrict__ zsrc, float* __restrict__ zdst,
                float* __restrict__ meansum, int haveHid){
    __shared__ float sz[4][HD];
    int tid = threadIdx.x;
    int m0 = blockIdx.x * 4;
    #pragma unroll
    for (int r = 0; r < 2; ++r){
        int idx = tid + r * 256;
        int mm = idx >> 7, n = idx & 127;
        float acc = be[n];
        const float* srow = state + (m0 + mm) * IND;
        #pragma unroll
        for (int k = 0; k < IND; ++k) acc += srow[k] * We[k * HD + n];
        if (haveHid){
            const float* hrow = hid + (m0 + mm) * HD;
            #pragma unroll
            for (int k = 0; k < HD; ++k) acc += hrow[k] * We[(IND + k) * HD + n];
        }
        z[(m0 + mm) * HD + n] = acc;
        sz[mm][n] = acc;
    }
    __syncthreads();
    #pragma unroll
    for (int r = 0; r < 2; ++r){
        int idx = tid + r * 256;
        int mm = idx >> 7, h = idx & 127;
        float accS = 0.f, accD = 0.f;
        #pragma unroll 8
        for (int k = 0; k < HD; ++k){
            float v = sz[mm][k];
            accS += v * Wm[k * HD + h];
            accD += v * Wm[(HD + k) * HD + h];
        }
        zsrc[(m0 + mm) * HD + h] = accS;
        zdst[(m0 + mm) * HD + h] = accD;
    }
    if (blockIdx.x == 0 && tid < HD) meansum[tid] = 0.f;
}

// ---------- MFMA msgmax: partial[c][j][h] = max_{i in chunk c} (zsrc[i,h] + edges[i,j,:]·WmE[:,h]) ----------
__global__ __launch_bounds__(256)
void msgmax_ker(const unsigned short* __restrict__ ebf, const float* __restrict__ zsrc,
                const float* __restrict__ Wm, float* __restrict__ partial){
    int lane = threadIdx.x & 63;
    int wv   = threadIdx.x >> 6;       // 0..3 -> h-tile
    int j0 = blockIdx.x * 32;
    int h0 = wv * 32;
    int i0 = blockIdx.y * CHUNK;
    int ln = lane & 31, lh = lane >> 5;

    // B fragment: B[k][n], n = h0+ln, k = 8*lh + q   (WmE = Wm rows 256..271)
    const float* WmE = Wm + 2 * HD * HD;
    short8 b;
    #pragma unroll
    for (int q = 0; q < 8; ++q)
        b[q] = (short)f2bf(WmE[(8 * lh + q) * HD + h0 + ln]);

    floatx16 czero;
    floatx16 run;
    #pragma unroll
    for (int r = 0; r < 16; ++r){ czero[r] = 0.f; run[r] = -INFINITY; }

    // A fragment: A[row][k] = edges_bf[i][j0+row][k], row = ln, k = 8*lh + q
    const unsigned short* abase = ebf + (size_t)(j0 + ln) * EFD + 8 * lh;

    for (int ii = 0; ii < CHUNK; ++ii){
        int i = i0 + ii;
        short8 a = *reinterpret_cast<const short8*>(abase + (size_t)i * NN * EFD);
        float zsv = zsrc[i * HD + h0 + ln];
        floatx16 d = __builtin_amdgcn_mfma_f32_32x32x16_bf16(a, b, czero, 0, 0, 0);
        #pragma unroll
        for (int r = 0; r < 16; ++r) run[r] = fmaxf(run[r], d[r] + zsv);
    }

    float* pb = partial + ((size_t)blockIdx.y * NN + j0) * HD + h0 + ln;
    #pragma unroll
    for (int r = 0; r < 16; ++r){
        int row = (r & 3) + 8 * (r >> 2) + 4 * lh;
        pb[(size_t)row * HD] = run[r];
    }
}

// ---------- h_new = [z | (max_c partial + zdst + bm)] @ Wu + bu ; mean partials ----------
__global__ void hnew_ker(const float* __restrict__ z, const float* __restrict__ zdst,
                         const float* __restrict__ partial, const float* __restrict__ bm,
                         const float* __restrict__ Wu, const float* __restrict__ bu,
                         float* __restrict__ hid, float* __restrict__ meansum){
    __shared__ float sA[2][256];
    __shared__ float sP[256];
    int tid = threadIdx.x;
    int m0 = blockIdx.x * 2;
    #pragma unroll
    for (int r = 0; r < 2; ++r){
        int idx = tid + r * 256;
        int mm = idx >> 8, k = idx & 255;
        float v;
        if (k < HD) v = z[(m0 + mm) * HD + k];
        else {
            int kk = k - HD;
            float mx = -INFINITY;
            #pragma unroll
            for (int c = 0; c < NC; ++c)
                mx = fmaxf(mx, partial[((size_t)c * NN + (m0 + mm)) * HD + kk]);
            v = mx + zdst[(m0 + mm) * HD + kk] + bm[kk];
        }
        sA[mm][k] = v;
    }
    __syncthreads();
    int h = tid & 127, mh = tid >> 7;
    float acc = bu[h];
    #pragma unroll 8
    for (int k = 0; k < 256; ++k) acc += sA[mh][k] * Wu[k * HD + h];
    hid[(m0 + mh) * HD + h] = acc;
    sP[tid] = acc;
    __syncthreads();
    if (mh == 0) atomicAdd(&meansum[h], sP[h] + sP[128 + h]);
}

// ---------- stop + new_state ----------
__global__ void out_ker(const float* __restrict__ hid, const float* __restrict__ z,
                        const float* __restrict__ meansum,
                        const float* __restrict__ Wt, const float* __restrict__ bt,
                        const float* __restrict__ Wd, const float* __restrict__ bd,
                        float* __restrict__ out, float* __restrict__ state_next, int t){
    __shared__ float sA[4][256];
    __shared__ float sM[128];
    int tid = threadIdx.x;
    int m0 = blockIdx.x * 4;
    #pragma unroll
    for (int r = 0; r < 4; ++r){
        int idx = tid + r * 256;
        int mm = idx >> 8, k = idx & 255;
        sA[mm][k] = (k < HD) ? hid[(m0 + mm) * HD + k] : z[(m0 + mm) * HD + (k - HD)];
    }
    if (tid < 128) sM[tid] = meansum[tid] * (1.0f / 768.0f);
    __syncthreads();

    int c = tid & 63, mm = tid >> 6;
    float acc = bd[c];
    #pragma unroll 8
    for (int k = 0; k < 256; ++k) acc += sA[mm][k] * Wd[k * IND + c];
    int m = m0 + mm;
    state_next[m * IND + c] = acc;
    out[m * 256 + (t + 1) * IND + c] = acc;

    if (tid < 8){
        int mml = tid >> 1, cc = tid & 1;
        int m2 = m0 + mml;
        float a2 = bt[cc];
        #pragma unroll 8
        for (int k = 0; k < HD; ++k) a2 += sA[mml][k] * Wt[k * 2 + cc];
        #pragma unroll 8
        for (int k = 0; k < HD; ++k) a2 += sM[k] * Wt[(HD + k) * 2 + cc];
        out[196608 + m2 * 8 + (t + 1) * 2 + cc] = 1.f / (1.f + expf(-a2));
    }
}

extern "C" void kernel_launch(void* const* d_in, const int* in_sizes, int n_in,
                              void* d_out, int out_size, void* d_ws, size_t ws_size,
                              hipStream_t stream){
    const float* states = (const float*)d_in[0];
    const float* edges  = (const float*)d_in[1];
    const float* We = (const float*)d_in[2];
    const float* be = (const float*)d_in[3];
    const float* Wm = (const float*)d_in[4];
    const float* bm = (const float*)d_in[5];
    const float* Wu = (const float*)d_in[6];
    const float* bu = (const float*)d_in[7];
    const float* Wd = (const float*)d_in[8];
    const float* bd = (const float*)d_in[9];
    const float* Wt = (const float*)d_in[10];
    const float* bt = (const float*)d_in[11];
    float* out = (float*)d_out;

    float* ws = (float*)d_ws;
    float*    z       = ws;                       // 98304
    float*    zsrc    = ws + 98304;               // 98304
    float*    zdst    = ws + 196608;              // 98304
    float*    hid     = ws + 294912;              // 98304
    float*    state   = ws + 393216;              // 49152
    float*    meansum = ws + 442368;              // 128 (+pad)
    float*    partial = ws + 442496;              // 16*768*128 = 1572864
    unsigned short* ebf = (unsigned short*)(ws + 2015360); // 9437184 bf16 = 18.9 MB

    conv_ker<<<9216, 256, 0, stream>>>(edges, ebf);
    init_ker<<<198, 256, 0, stream>>>(states, out);

    for (int t = 0; t < TT; ++t){
        const float* st = (t == 0) ? states : state;
        zfused_ker<<<192, 256, 0, stream>>>(st, hid, We, be, Wm, z, zsrc, zdst, meansum, t > 0 ? 1 : 0);
        msgmax_ker<<<dim3(24, NC), 256, 0, stream>>>(ebf, zsrc, Wm, partial);
        hnew_ker<<<384, 256, 0, stream>>>(z, zdst, partial, bm, Wu, bu, hid, meansum);
        out_ker<<<192, 256, 0, stream>>>(hid, z, meansum, Wt, bt, Wd, bd, out, state, t);
    }
}

// Round 3
// 207.524 us; speedup vs baseline: 1.6892x; 1.3116x over previous
//
#include <hip/hip_runtime.h>
#include <cstdint>
#include <cstddef>

#define NN  768
#define IND 64
#define HD  128
#define EFD 16
#define TT  3
#define NC  32      // i-chunks in msgmax
#define CHUNK 24    // 768/NC

typedef __attribute__((ext_vector_type(8)))  short short8;
typedef __attribute__((ext_vector_type(16))) float floatx16;

__device__ __forceinline__ unsigned short f2bf(float f){
    unsigned u = __float_as_uint(f);
    unsigned r = (u + 0x7FFFu + ((u >> 16) & 1u)) >> 16;
    return (unsigned short)r;
}

// ---------- one-time: edges f32 -> bf16 ----------
__global__ void conv_ker(const float* __restrict__ e, unsigned short* __restrict__ ebf){
    int gid = blockIdx.x * 256 + threadIdx.x;          // 2359296 threads, 4 elems each
    const float4 v = reinterpret_cast<const float4*>(e)[gid];
    uint2 p;
    p.x = (unsigned)f2bf(v.x) | ((unsigned)f2bf(v.y) << 16);
    p.y = (unsigned)f2bf(v.z) | ((unsigned)f2bf(v.w) << 16);
    reinterpret_cast<uint2*>(ebf)[gid] = p;
}

// ---------- init: preds[:,0,:] = state0, preds_stop[:,0,:] = 0 ----------
__global__ void init_ker(const float* __restrict__ states, float* __restrict__ out){
    int i = blockIdx.x * 256 + threadIdx.x;
    if (i < NN * IND){
        int n = i >> 6, c = i & 63;
        out[n * 256 + c] = states[i];
    } else if (i < NN * IND + NN * 2){
        int j = i - NN * IND;
        int n = j >> 1, cc = j & 1;
        out[196608 + n * 8 + cc] = 0.f;
    }
}

// ---------- z = [state|hidden] @ We + be ; zeros meansum ----------
__global__ void z_ker(const float* __restrict__ state, const float* __restrict__ hid,
                      const float* __restrict__ We, const float* __restrict__ be,
                      float* __restrict__ z, float* __restrict__ meansum, int haveHid){
    int tid = threadIdx.x;
    int n = tid & 127, mh = tid >> 7;
    int m = blockIdx.x * 2 + mh;
    float acc = be[n];
    const float* srow = state + m * IND;
    #pragma unroll
    for (int k = 0; k < IND; ++k) acc += srow[k] * We[k * HD + n];
    if (haveHid){
        const float* hrow = hid + m * HD;
        #pragma unroll
        for (int k = 0; k < HD; ++k) acc += hrow[k] * We[(IND + k) * HD + n];
    }
    z[m * HD + n] = acc;
    if (blockIdx.x == 0 && mh == 0) meansum[n] = 0.f;
}

// ---------- zsrc = z @ Wm[:128], zdst = z @ Wm[128:256] ----------
__global__ void zsd_ker(const float* __restrict__ z, const float* __restrict__ Wm,
                        float* __restrict__ zsrc, float* __restrict__ zdst){
    int tid = threadIdx.x;
    int h = tid & 127, which = tid >> 7;
    int m = blockIdx.x;
    const float* zrow = z + m * HD;
    const float* W = Wm + which * HD * HD;
    float acc = 0.f;
    #pragma unroll
    for (int k = 0; k < HD; ++k) acc += zrow[k] * W[k * HD + h];
    (which ? zdst : zsrc)[m * HD + h] = acc;
}

// ---------- MFMA msgmax: partial[c][j][h] = max_{i in chunk c} (zsrc[i,h] + edges[i,j,:]·WmE[:,h]) ----------
__global__ __launch_bounds__(256)
void msgmax_ker(const unsigned short* __restrict__ ebf, const float* __restrict__ zsrc,
                const float* __restrict__ Wm, float* __restrict__ partial){
    int lane = threadIdx.x & 63;
    int wv   = threadIdx.x >> 6;       // 0..3 -> h-tile
    int j0 = blockIdx.x * 32;
    int h0 = wv * 32;
    int i0 = blockIdx.y * CHUNK;
    int ln = lane & 31, lh = lane >> 5;

    // B fragment: B[k][n], n = h0+ln, k = 8*lh + q   (WmE = Wm rows 256..271)
    const float* WmE = Wm + 2 * HD * HD;
    short8 b;
    #pragma unroll
    for (int q = 0; q < 8; ++q)
        b[q] = (short)f2bf(WmE[(8 * lh + q) * HD + h0 + ln]);

    floatx16 czero;
    floatx16 run;
    #pragma unroll
    for (int r = 0; r < 16; ++r){ czero[r] = 0.f; run[r] = -INFINITY; }

    // A fragment: A[row][k] = edges_bf[i][j0+row][k], row = ln, k = 8*lh + q
    const unsigned short* abase = ebf + (size_t)(j0 + ln) * EFD + 8 * lh;

    #pragma unroll 2
    for (int ii = 0; ii < CHUNK; ++ii){
        int i = i0 + ii;
        short8 a = *reinterpret_cast<const short8*>(abase + (size_t)i * NN * EFD);
        float zsv = zsrc[i * HD + h0 + ln];
        floatx16 d = __builtin_amdgcn_mfma_f32_32x32x16_bf16(a, b, czero, 0, 0, 0);
        #pragma unroll
        for (int r = 0; r < 16; ++r) run[r] = fmaxf(run[r], d[r] + zsv);
    }

    float* pb = partial + ((size_t)blockIdx.y * NN + j0) * HD + h0 + ln;
    #pragma unroll
    for (int r = 0; r < 16; ++r){
        int row = (r & 3) + 8 * (r >> 2) + 4 * lh;
        pb[(size_t)row * HD] = run[r];
    }
}

// ---------- h_new = [z | (max_c partial + zdst + bm)] @ Wu + bu ; mean partials ----------
__global__ void hnew_ker(const float* __restrict__ z, const float* __restrict__ zdst,
                         const float* __restrict__ partial, const float* __restrict__ bm,
                         const float* __restrict__ Wu, const float* __restrict__ bu,
                         float* __restrict__ hid, float* __restrict__ meansum){
    __shared__ float sA[2][256];
    __shared__ float sP[256];
    int tid = threadIdx.x;
    int m0 = blockIdx.x * 2;
    #pragma unroll
    for (int r = 0; r < 2; ++r){
        int idx = tid + r * 256;
        int mm = idx >> 8, k = idx & 255;
        float v;
        if (k < HD) v = z[(m0 + mm) * HD + k];
        else {
            int kk = k - HD;
            float mx = -INFINITY;
            #pragma unroll
            for (int c = 0; c < NC; ++c)
                mx = fmaxf(mx, partial[((size_t)c * NN + (m0 + mm)) * HD + kk]);
            v = mx + zdst[(m0 + mm) * HD + kk] + bm[kk];
        }
        sA[mm][k] = v;
    }
    __syncthreads();
    int h = tid & 127, mh = tid >> 7;
    float acc = bu[h];
    #pragma unroll 8
    for (int k = 0; k < 256; ++k) acc += sA[mh][k] * Wu[k * HD + h];
    hid[(m0 + mh) * HD + h] = acc;
    sP[tid] = acc;
    __syncthreads();
    if (mh == 0) atomicAdd(&meansum[h], sP[h] + sP[128 + h]);
}

// ---------- stop + new_state ----------
__global__ void out_ker(const float* __restrict__ hid, const float* __restrict__ z,
                        const float* __restrict__ meansum,
                        const float* __restrict__ Wt, const float* __restrict__ bt,
                        const float* __restrict__ Wd, const float* __restrict__ bd,
                        float* __restrict__ out, float* __restrict__ state_next, int t){
    __shared__ float sA[4][256];
    __shared__ float sM[128];
    int tid = threadIdx.x;
    int m0 = blockIdx.x * 4;
    #pragma unroll
    for (int r = 0; r < 4; ++r){
        int idx = tid + r * 256;
        int mm = idx >> 8, k = idx & 255;
        sA[mm][k] = (k < HD) ? hid[(m0 + mm) * HD + k] : z[(m0 + mm) * HD + (k - HD)];
    }
    if (tid < 128) sM[tid] = meansum[tid] * (1.0f / 768.0f);
    __syncthreads();

    int c = tid & 63, mm = tid >> 6;
    float acc = bd[c];
    #pragma unroll 8
    for (int k = 0; k < 256; ++k) acc += sA[mm][k] * Wd[k * IND + c];
    int m = m0 + mm;
    state_next[m * IND + c] = acc;
    out[m * 256 + (t + 1) * IND + c] = acc;

    if (tid < 8){
        int mml = tid >> 1, cc = tid & 1;
        int m2 = m0 + mml;
        float a2 = bt[cc];
        #pragma unroll 8
        for (int k = 0; k < HD; ++k) a2 += sA[mml][k] * Wt[k * 2 + cc];
        #pragma unroll 8
        for (int k = 0; k < HD; ++k) a2 += sM[k] * Wt[(HD + k) * 2 + cc];
        out[196608 + m2 * 8 + (t + 1) * 2 + cc] = 1.f / (1.f + expf(-a2));
    }
}

extern "C" void kernel_launch(void* const* d_in, const int* in_sizes, int n_in,
                              void* d_out, int out_size, void* d_ws, size_t ws_size,
                              hipStream_t stream){
    const float* states = (const float*)d_in[0];
    const float* edges  = (const float*)d_in[1];
    const float* We = (const float*)d_in[2];
    const float* be = (const float*)d_in[3];
    const float* Wm = (const float*)d_in[4];
    const float* bm = (const float*)d_in[5];
    const float* Wu = (const float*)d_in[6];
    const float* bu = (const float*)d_in[7];
    const float* Wd = (const float*)d_in[8];
    const float* bd = (const float*)d_in[9];
    const float* Wt = (const float*)d_in[10];
    const float* bt = (const float*)d_in[11];
    float* out = (float*)d_out;

    float* ws = (float*)d_ws;
    float*    z       = ws;                       // 98304
    float*    zsrc    = ws + 98304;               // 98304
    float*    zdst    = ws + 196608;              // 98304
    float*    hid     = ws + 294912;              // 98304
    float*    state   = ws + 393216;              // 49152
    float*    meansum = ws + 442368;              // 128 (+pad)
    float*    partial = ws + 442496;              // 32*768*128 = 3145728
    unsigned short* ebf = (unsigned short*)(ws + 3588224); // 9437184 bf16 = 18.9 MB

    conv_ker<<<9216, 256, 0, stream>>>(edges, ebf);
    init_ker<<<198, 256, 0, stream>>>(states, out);

    for (int t = 0; t < TT; ++t){
        const float* st = (t == 0) ? states : state;
        z_ker<<<384, 256, 0, stream>>>(st, hid, We, be, z, meansum, t > 0 ? 1 : 0);
        zsd_ker<<<768, 256, 0, stream>>>(z, Wm, zsrc, zdst);
        msgmax_ker<<<dim3(24, NC), 256, 0, stream>>>(ebf, zsrc, Wm, partial);
        hnew_ker<<<384, 256, 0, stream>>>(z, zdst, partial, bm, Wu, bu, hid, meansum);
        out_ker<<<192, 256, 0, stream>>>(hid, z, meansum, Wt, bt, Wd, bd, out, state, t);
    }
}